// Round 1
// 248.251 us; speedup vs baseline: 1.1680x; 1.1680x over previous
//
#include <hip/hip_runtime.h>
#include <hip/hip_bf16.h>
#include <math.h>

#define B_   4
#define C_   192
#define N_   6400
#define K_   9
#define M_   50
#define TK_  12
#define OC_  192
#define KC_  576     // 3*C
#define CH_  100     // 64-point chunks per batch
#define LSTR 53      // padded lg row stride (fp32; odd -> conflict-free)
#define TSTR 72      // lgT row stride (bf16)
#define XSTR 40      // xT row stride (bf16), 80 B, 16B-aligned
#define GSTR 40      // k_gemm bf16 LDS row stride
#define GPB  8       // points per k_gather block

typedef __bf16 b16x8 __attribute__((ext_vector_type(8)));
typedef float f32x4 __attribute__((ext_vector_type(4)));

__device__ inline unsigned short f2b(float f) {
    union { __hip_bfloat16 h; unsigned short u; } v;
    v.h = __float2bfloat16(f);
    return v.u;
}
__device__ inline float b2f(unsigned short u) {
    union { float f; unsigned int i; } v;
    v.i = ((unsigned int)u) << 16;
    return v.f;
}
__device__ inline void up8(uint4 v, float* f) {
    unsigned int w[4] = {v.x, v.y, v.z, v.w};
#pragma unroll
    for (int i = 0; i < 4; i++) {
        f[2 * i]     = b2f((unsigned short)(w[i] & 0xffffu));
        f[2 * i + 1] = b2f((unsigned short)(w[i] >> 16));
    }
}
__device__ inline uint4 pack8(const float* f) {
    unsigned int w[4];
#pragma unroll
    for (int i = 0; i < 4; i++)
        w[i] = (unsigned int)f2b(f[2 * i]) | ((unsigned int)f2b(f[2 * i + 1]) << 16);
    uint4 v; v.x = w[0]; v.y = w[1]; v.z = w[2]; v.w = w[3];
    return v;
}

// -------- transpose x (b,c,n) -> xt fp32 + xt16/xt16l (bf16 hi/lo)
//          + merged W re-permute (blocks with blockIdx.x >= 200) -------------
__global__ void k_transpose(const float* __restrict__ x, float* __restrict__ xt,
                            unsigned short* __restrict__ xt16,
                            unsigned short* __restrict__ xt16l,
                            const float* __restrict__ cw,
                            unsigned short* __restrict__ Wg16) {
    int tid = threadIdx.y * 32 + threadIdx.x;
    if (blockIdx.x >= 200) {
        // Wg16[o][t*192+ch] = conv_w[o][ch*3+t];  432 blocks x 256 = 110592
        int g = ((blockIdx.x - 200) * 24 + blockIdx.z * 6 + blockIdx.y) * 256 + tid;
        if (g < OC_ * KC_) {
            int r = g % KC_;
            Wg16[g] = f2b(cw[(g / KC_) * KC_ + (r % C_) * 3 + (r / C_)]);
        }
        return;
    }
    __shared__ float tile[32][33];
    int b = blockIdx.z;
    int p0 = blockIdx.x * 32, c0 = blockIdx.y * 32;
    int tx = threadIdx.x, ty = threadIdx.y;
    const float* xb = x + (size_t)b * C_ * N_;
    float* xtb = xt + (size_t)b * N_ * C_;
    unsigned short* xt16b = xt16 + (size_t)b * N_ * C_;
    unsigned short* xt16lb = xt16l + (size_t)b * N_ * C_;
#pragma unroll
    for (int i = 0; i < 4; i++) {
        int cc = ty + 8 * i;
        tile[cc][tx] = xb[(size_t)(c0 + cc) * N_ + p0 + tx];
    }
    __syncthreads();
#pragma unroll
    for (int i = 0; i < 4; i++) {
        int pp = ty + 8 * i;
        float v = tile[tx][pp];
        size_t o = (size_t)(p0 + pp) * C_ + c0 + tx;
        xtb[o] = v;
        unsigned short hi = f2b(v);
        xt16b[o] = hi;
        xt16lb[o] = f2b(v - b2f(hi));
    }
}

// -- initial centroids: 5x10 pool (+ |c|^2, + hi/lo split, zero pad rows) -----
__global__ __launch_bounds__(192) void k_init_cent(const float* __restrict__ xt,
        float* __restrict__ cent, float* __restrict__ c2,
        unsigned short* __restrict__ centh, unsigned short* __restrict__ centl) {
    int m = blockIdx.x, b = blockIdx.y, c = threadIdx.x;
    if (m >= M_) {   // zero-pad rows 50..63 of the split arrays
        size_t o = ((size_t)b * 64 + m) * C_ + c;
        centh[o] = 0; centl[o] = 0;
        return;
    }
    int gy = m / 10, gx = m % 10;
    const float* xtb = xt + (size_t)b * N_ * C_;
    float s = 0.f;
    for (int yy = 0; yy < 16; yy++)
        for (int xx = 0; xx < 8; xx++) {
            int p = (gy * 16 + yy) * 80 + gx * 8 + xx;
            s += xtb[(size_t)p * C_ + c];
        }
    float v = s * (1.f / 128.f);
    cent[((size_t)b * M_ + m) * C_ + c] = v;
    size_t oh = ((size_t)b * 64 + m) * C_ + c;
    unsigned short hi = f2b(v);
    centh[oh] = hi;
    centl[oh] = f2b(v - b2f(hi));
    float q = v * v;
    __shared__ float red[3];
#pragma unroll
    for (int off = 32; off > 0; off >>= 1) q += __shfl_down(q, off, 64);
    if ((c & 63) == 0) red[c >> 6] = q;
    __syncthreads();
    if (c == 0) c2[(size_t)b * M_ + m] = red[0] + red[1] + red[2];
}

// ==== fused: logits (direct-global MFMA fast path / fp32 exact path) +
//      softmax + bf16-split MFMA partials (+ topk on last iter) ==============
__global__ __launch_bounds__(256) void k_logits_upd(const float* __restrict__ xt,
        const unsigned short* __restrict__ xt16, const unsigned short* __restrict__ xt16l,
        const float* __restrict__ cent,
        const unsigned short* __restrict__ centh, const unsigned short* __restrict__ centl,
        const float* __restrict__ c2g,
        unsigned short* __restrict__ part, float* __restrict__ wsp,
        int* __restrict__ nn, int do_topk, int fast) {
    __shared__ alignas(16) char smem[51712];
    __shared__ float sred[256];
    float* Ac = (float*)smem;                             // fp32 path staging
    float* Bp = (float*)(smem + 4352);
    float* lg = (float*)(smem + 20480);
    unsigned short* lgTh = (unsigned short*)smem;
    unsigned short* lgTl = (unsigned short*)(smem + 9216);
    unsigned short* xTh = (unsigned short*)(smem + 18432);
    unsigned short* xTl = (unsigned short*)(smem + 35072);
    int b = blockIdx.y;
    int blk = blockIdx.x;
    int p0 = blk * 64;
    int tid = threadIdx.x;
    int tx = tid & 15, ty = tid >> 4;
    int lr = tid >> 2, lq = tid & 3;
    int wave = tid >> 6, lane = tid & 63;
    int m16 = lane & 15, q = lane >> 4;
    const float* xb = xt + ((size_t)b * N_ + p0) * C_;
    const unsigned short* x16b = xt16 + ((size_t)b * N_ + p0) * C_;
    const unsigned short* x16lb = xt16l + ((size_t)b * N_ + p0) * C_;
    if (fast) {
        // ---- phase 1 fast: split-bf16 MFMA logits, fragments direct from
        //      global (xt16/centh already in [row][k] fragment layout) ----
        const unsigned short* chg = centh + (size_t)b * 64 * C_;
        const unsigned short* clg = centl + (size_t)b * 64 * C_;
        f32x4 acc1[4];
#pragma unroll
        for (int i = 0; i < 4; i++) acc1[i] = (f32x4){0.f, 0.f, 0.f, 0.f};
#pragma unroll
        for (int kt = 0; kt < 6; kt++) {
            int kg = kt * 32;
            size_t xo = (size_t)(wave * 16 + m16) * C_ + kg + q * 8;
            b16x8 bh = *(const b16x8*)&x16b[xo];
            b16x8 bl = *(const b16x8*)&x16lb[xo];
#pragma unroll
            for (int mt = 0; mt < 4; mt++) {
                size_t co = (size_t)(mt * 16 + m16) * C_ + kg + q * 8;
                b16x8 ah = *(const b16x8*)&chg[co];
                b16x8 al = *(const b16x8*)&clg[co];
                acc1[mt] = __builtin_amdgcn_mfma_f32_16x16x32_bf16(ah, bh, acc1[mt], 0, 0, 0);
                acc1[mt] = __builtin_amdgcn_mfma_f32_16x16x32_bf16(ah, bl, acc1[mt], 0, 0, 0);
                acc1[mt] = __builtin_amdgcn_mfma_f32_16x16x32_bf16(al, bh, acc1[mt], 0, 0, 0);
            }
        }
        // D row m = mt*16+q*4+r, col p = wave*16+m16
#pragma unroll
        for (int mt = 0; mt < 4; mt++) {
#pragma unroll
            for (int r = 0; r < 4; r++) {
                int m = mt * 16 + q * 4 + r;
                if (m < M_) {
                    float c2v = c2g[(size_t)b * M_ + m];
                    lg[(wave * 16 + m16) * LSTR + m] = 2.f * acc1[mt][r] - c2v;
                }
            }
        }
    } else {
        // ---- phase 1 exact: fp32 VALU logits (iter 2 -> topk) ----
        const float* cb = cent + (size_t)b * M_ * C_;
        float acc[4][4];
#pragma unroll
        for (int i = 0; i < 4; i++)
#pragma unroll
            for (int j = 0; j < 4; j++) acc[i][j] = 0.f;
        for (int kt = 0; kt < 12; kt++) {
            int kg = kt * 16;
            float4 cv = make_float4(0.f, 0.f, 0.f, 0.f);
            if (lr < M_) cv = *(const float4*)&cb[(size_t)lr * C_ + kg + 4 * lq];
            float4 pv = *(const float4*)&xb[(size_t)lr * C_ + kg + 4 * lq];
            __syncthreads();
            Ac[(4 * lq + 0) * 68 + lr] = cv.x; Ac[(4 * lq + 1) * 68 + lr] = cv.y;
            Ac[(4 * lq + 2) * 68 + lr] = cv.z; Ac[(4 * lq + 3) * 68 + lr] = cv.w;
            Bp[(4 * lq + 0) * 68 + lr] = pv.x; Bp[(4 * lq + 1) * 68 + lr] = pv.y;
            Bp[(4 * lq + 2) * 68 + lr] = pv.z; Bp[(4 * lq + 3) * 68 + lr] = pv.w;
            __syncthreads();
#pragma unroll
            for (int kk = 0; kk < 16; kk++) {
                float4 a = *(const float4*)&Ac[kk * 68 + 4 * ty];
                float4 bb = *(const float4*)&Bp[kk * 68 + 4 * tx];
                acc[0][0] += a.x * bb.x; acc[0][1] += a.x * bb.y; acc[0][2] += a.x * bb.z; acc[0][3] += a.x * bb.w;
                acc[1][0] += a.y * bb.x; acc[1][1] += a.y * bb.y; acc[1][2] += a.y * bb.z; acc[1][3] += a.y * bb.w;
                acc[2][0] += a.z * bb.x; acc[2][1] += a.z * bb.y; acc[2][2] += a.z * bb.z; acc[2][3] += a.z * bb.w;
                acc[3][0] += a.w * bb.x; acc[3][1] += a.w * bb.y; acc[3][2] += a.w * bb.z; acc[3][3] += a.w * bb.w;
            }
        }
        __syncthreads();
#pragma unroll
        for (int i = 0; i < 4; i++) {
            int m = 4 * ty + i;
            if (m < M_) {
                float c2v = c2g[(size_t)b * M_ + m];
#pragma unroll
                for (int j = 0; j < 4; j++)
                    lg[(4 * tx + j) * LSTR + m] = 2.f * acc[i][j] - c2v;
            }
        }
    }
    __syncthreads();
    // ---- softmax (4-way parallel per row) ----
    {
        int p = tid & 63, prt = tid >> 6;
        int m0 = prt * 13;
        int m1 = (prt == 3) ? M_ : m0 + 13;
        float* row = &lg[p * LSTR];
        float mx = -1e30f;
        for (int m = m0; m < m1; m++) mx = fmaxf(mx, row[m]);
        sred[prt * 64 + p] = mx;
        __syncthreads();
        mx = fmaxf(fmaxf(sred[p], sred[64 + p]), fmaxf(sred[128 + p], sred[192 + p]));
        float s = 0.f;
        for (int m = m0; m < m1; m++) {
            float e = expf(row[m] - mx);
            row[m] = e;
            s += e;
        }
        __syncthreads();
        sred[prt * 64 + p] = s;
        __syncthreads();
        s = sred[p] + sred[64 + p] + sred[128 + p] + sred[192 + p];
        float inv = 1.f / s;
        for (int m = m0; m < m1; m++) row[m] *= inv;
    }
    __syncthreads();
    // ---- build lgT[m][p] hi/lo bf16 (lane-consecutive p: conflict-free) ----
    for (int j = tid; j < 64 * 64; j += 256) {
        int m = j >> 6, p = j & 63;
        float w = (m < M_) ? lg[p * LSTR + m] : 0.f;
        unsigned short hi = f2b(w);
        lgTh[m * TSTR + p] = hi;
        lgTl[m * TSTR + p] = f2b(w - b2f(hi));
    }
    __syncthreads();
    // ---- topk on last iteration (reads+destroys lg; before xT overwrites) ---
    if (do_topk && tid < 64) {
        float* row = &lg[tid * LSTR];
        int* nb = nn + ((size_t)b * N_ + p0 + tid) * TK_;
        for (int r = 0; r < TK_; r++) {
            float bv = -1.f;
            int bi = 0;
            for (int m = 0; m < M_; m++) {
                float v = row[m];
                if (v > bv) { bv = v; bi = m; }   // strict > : lowest index wins ties
            }
            nb[r] = bi;
            row[bi] = -1.f;
        }
    }
    // ---- phase 2: part[m][c] = sum_p w*x via 3-term bf16-split MFMA ----
    f32x4 acc2[13];
#pragma unroll
    for (int i = 0; i < 13; i++) acc2[i] = (f32x4){0.f, 0.f, 0.f, 0.f};
    for (int h = 0; h < 2; h++) {
        __syncthreads();   // lg/topk done (h=0); prev MFMA reads done (h=1)
        // xT build: lanes consecutive pl -> contiguous b16 writes (no conflict)
        for (int j = tid; j < 32 * 24; j += 256) {
            int pl = j & 31, ko = (j >> 5) * 8;
            int4 vh = *(const int4*)&x16b[(size_t)(h * 32 + pl) * C_ + ko];
            int4 vl = *(const int4*)&x16lb[(size_t)(h * 32 + pl) * C_ + ko];
            const unsigned short* ph = (const unsigned short*)&vh;
            const unsigned short* pv = (const unsigned short*)&vl;
#pragma unroll
            for (int i = 0; i < 8; i++) {
                xTh[(ko + i) * XSTR + pl] = ph[i];
                xTl[(ko + i) * XSTR + pl] = pv[i];
            }
        }
        for (int j = tid; j < 32 * 16; j += 256) {
            int pl = j & 31, c = C_ + (j >> 5);
            xTh[c * XSTR + pl] = (c == C_) ? f2b(1.f) : 0;
            xTl[c * XSTR + pl] = 0;
        }
        __syncthreads();
        b16x8 ah = *(const b16x8*)&lgTh[(wave * 16 + m16) * TSTR + h * 32 + q * 8];
        b16x8 al = *(const b16x8*)&lgTl[(wave * 16 + m16) * TSTR + h * 32 + q * 8];
#pragma unroll
        for (int ct = 0; ct < 13; ct++) {
            b16x8 bh = *(const b16x8*)&xTh[(ct * 16 + m16) * XSTR + q * 8];
            b16x8 bl = *(const b16x8*)&xTl[(ct * 16 + m16) * XSTR + q * 8];
            acc2[ct] = __builtin_amdgcn_mfma_f32_16x16x32_bf16(ah, bh, acc2[ct], 0, 0, 0);
            acc2[ct] = __builtin_amdgcn_mfma_f32_16x16x32_bf16(ah, bl, acc2[ct], 0, 0, 0);
            acc2[ct] = __builtin_amdgcn_mfma_f32_16x16x32_bf16(al, bh, acc2[ct], 0, 0, 0);
        }
    }
    // ---- epilogue: D row m = wave*16 + q*4 + r, col c = ct*16 + m16 ----
    unsigned short* pb = part + ((size_t)b * CH_ + blk) * (size_t)(M_ * C_);
    int mbase = wave * 16 + q * 4;
#pragma unroll
    for (int ct = 0; ct < 13; ct++) {
        int c = ct * 16 + m16;
#pragma unroll
        for (int r = 0; r < 4; r++) {
            int mm = mbase + r;
            if (mm >= M_) continue;
            float v = acc2[ct][r];
            if (c < C_) pb[(size_t)mm * C_ + c] = f2b(v);
            else if (c == C_) wsp[((size_t)b * CH_ + blk) * M_ + mm] = v;
        }
    }
}

// ---- chunk reduction: 2-way chunk split (384 thr) + wave-parallel wsp sum ---
__global__ __launch_bounds__(384) void k_upd_reduce(const unsigned short* __restrict__ part,
        const float* __restrict__ wsp, float* __restrict__ cent, float* __restrict__ c2,
        unsigned short* __restrict__ cent16,
        unsigned short* __restrict__ centh, unsigned short* __restrict__ centl, int last) {
    int m = blockIdx.x, b = blockIdx.y;
    int tid = threadIdx.x;
    int c = tid % 192, g = tid / 192;
    __shared__ float pred[192];
    __shared__ float sws;
    __shared__ float red[3];
    // each half sums 50 of the 100 chunks
    const unsigned short* pp = part + (((size_t)b * CH_ + (size_t)g * 50) * M_ + m) * (size_t)C_ + c;
    float s = 0.f;
    for (int ch = 0; ch < 50; ch++)
        s += b2f(pp[(size_t)ch * M_ * C_]);
    if (g == 1) pred[c] = s;
    // wave-parallel wsp reduction (lanes 0..63 cover 100 chunks in <=2 loads)
    if (tid < 64) {
        float w = wsp[((size_t)b * CH_ + tid) * M_ + m];
        if (tid + 64 < CH_) w += wsp[((size_t)b * CH_ + tid + 64) * M_ + m];
#pragma unroll
        for (int off = 32; off > 0; off >>= 1) w += __shfl_down(w, off, 64);
        if (tid == 0) sws = w + 1e-8f;
    }
    __syncthreads();
    if (g == 0) {
        float v = (s + pred[c]) / sws;
        size_t o = ((size_t)b * M_ + m) * C_ + c;
        cent[o] = v;
        if (last) cent16[o] = f2b(v);
        size_t oh = ((size_t)b * 64 + m) * C_ + c;
        unsigned short hi = f2b(v);
        centh[oh] = hi;
        centl[oh] = f2b(v - b2f(hi));
        float q = v * v;
#pragma unroll
        for (int off = 32; off > 0; off >>= 1) q += __shfl_down(q, off, 64);
        if ((c & 63) == 0) red[c >> 6] = q;
    }
    __syncthreads();
    if (tid == 0) c2[(size_t)b * M_ + m] = red[0] + red[1] + red[2];
}

// ---------------- gathers (bf16 sources): edge max-rel + topk-centroid max ---
// vectorized: uint4 = 8 channels/lane, 24 lanes/point, 8 points/block
__global__ __launch_bounds__(192) void k_gather(const unsigned short* __restrict__ xt16,
        const unsigned short* __restrict__ cent16, const int* __restrict__ edge,
        const int* __restrict__ nn, unsigned short* __restrict__ xjt16,
        unsigned short* __restrict__ xjct16) {
    __shared__ int sidx[GPB * (2 * K_ + TK_)];
    int b = blockIdx.y;
    int p0 = blockIdx.x * GPB;
    int tid = threadIdx.x;
    for (int j = tid; j < GPB * (2 * K_ + TK_); j += 192) {
        int g = j / (2 * K_ + TK_), r = j % (2 * K_ + TK_);
        size_t base = (size_t)b * N_ + p0 + g;
        int v;
        if (r < K_) v = edge[base * K_ + r];
        else if (r < 2 * K_) v = edge[(size_t)B_ * N_ * K_ + base * K_ + (r - K_)];
        else v = nn[base * TK_ + (r - 2 * K_)];
        sidx[j] = v;
    }
    __syncthreads();
    int g = tid / 24, t = tid % 24;
    int ch0 = t * 8;
    int p = p0 + g;
    const unsigned short* xb = xt16 + (size_t)b * N_ * C_;
    const unsigned short* cb = cent16 + (size_t)b * M_ * C_;
    const int* si = &sidx[g * (2 * K_ + TK_)];
    float xv[8], ta[8], tb[8], mj[8], mc[8];
    up8(*(const uint4*)&xb[(size_t)p * C_ + ch0], xv);
#pragma unroll
    for (int e = 0; e < 8; e++) { mj[e] = -1e30f; mc[e] = -1e30f; }
#pragma unroll
    for (int kk = 0; kk < K_; kk++) {
        up8(*(const uint4*)&xb[(size_t)si[kk] * C_ + ch0], ta);
        up8(*(const uint4*)&xb[(size_t)si[K_ + kk] * C_ + ch0], tb);
#pragma unroll
        for (int e = 0; e < 8; e++) mj[e] = fmaxf(mj[e], ta[e] - tb[e]);
    }
#pragma unroll
    for (int kk = 0; kk < TK_; kk++) {
        up8(*(const uint4*)&cb[(size_t)si[2 * K_ + kk] * C_ + ch0], ta);
#pragma unroll
        for (int e = 0; e < 8; e++) mc[e] = fmaxf(mc[e], ta[e]);
    }
#pragma unroll
    for (int e = 0; e < 8; e++) mc[e] -= xv[e];
    size_t o = ((size_t)b * N_ + p) * C_ + ch0;
    *(uint4*)&xjt16[o] = pack8(mj);
    *(uint4*)&xjct16[o] = pack8(mc);
}

// ------- final conv via bf16 MFMA: full-OC 192(o) x 64(p) tile, feat read once
__global__ __launch_bounds__(256) void k_gemm(const unsigned short* __restrict__ Wg16,
        const unsigned short* __restrict__ xt16, const unsigned short* __restrict__ xjt16,
        const unsigned short* __restrict__ xjct16, const float* __restrict__ bias,
        float* __restrict__ out) {
    __shared__ short As[192 * GSTR];   // Wg k-chunk [o][32k]
    __shared__ short Bs[64 * GSTR];    // feat k-chunk [p][32k]
    int b = blockIdx.y;
    int po = blockIdx.x * 64;
    int tid = threadIdx.x;
    int wave = tid >> 6, lane = tid & 63;
    int m16 = lane & 15, q = lane >> 4;
    const unsigned short* s0 = xt16 + (size_t)b * N_ * C_;
    const unsigned short* s1 = xjt16 + (size_t)b * N_ * C_;
    const unsigned short* s2 = xjct16 + (size_t)b * N_ * C_;
    f32x4 acc[12];
#pragma unroll
    for (int i = 0; i < 12; i++) acc[i] = (f32x4){0.f, 0.f, 0.f, 0.f};
    int brow = tid >> 2, bch = tid & 3;
    for (int kt = 0; kt < 18; kt++) {
        int kg = kt * 32;
        int prt = kg / C_, koff = kg - prt * C_;
        const unsigned short* src = (prt == 0) ? s0 : ((prt == 1) ? s1 : s2);
        int4 av[3];
#pragma unroll
        for (int t = 0; t < 3; t++) {
            int idx = t * 256 + tid;
            av[t] = *(const int4*)&Wg16[(size_t)(idx >> 2) * KC_ + kg + (idx & 3) * 8];
        }
        int4 bv = *(const int4*)&src[(size_t)(po + brow) * C_ + koff + bch * 8];
        __syncthreads();
#pragma unroll
        for (int t = 0; t < 3; t++) {
            int idx = t * 256 + tid;
            *(int4*)&As[(idx >> 2) * GSTR + (idx & 3) * 8] = av[t];
        }
        *(int4*)&Bs[brow * GSTR + bch * 8] = bv;
        __syncthreads();
        b16x8 bf = *(const b16x8*)&Bs[(wave * 16 + m16) * GSTR + q * 8];
#pragma unroll
        for (int of = 0; of < 12; of++) {
            b16x8 af = *(const b16x8*)&As[(of * 16 + m16) * GSTR + q * 8];
            acc[of] = __builtin_amdgcn_mfma_f32_16x16x32_bf16(af, bf, acc[of], 0, 0, 0);
        }
    }
    int p = po + wave * 16 + m16;
#pragma unroll
    for (int of = 0; of < 12; of++) {
        int o = of * 16 + q * 4;
        float4 bv = *(const float4*)&bias[o];
        float bia[4] = {bv.x, bv.y, bv.z, bv.w};
#pragma unroll
        for (int r = 0; r < 4; r++)
            out[((size_t)b * OC_ + o + r) * N_ + p] = fmaxf(acc[of][r] + bia[r], 0.f);
    }
}

extern "C" void kernel_launch(void* const* d_in, const int* in_sizes, int n_in,
                              void* d_out, int out_size, void* d_ws, size_t ws_size,
                              hipStream_t stream) {
    (void)in_sizes; (void)n_in; (void)out_size; (void)ws_size;
    const float* x   = (const float*)d_in[0];
    const int* edge  = (const int*)d_in[1];
    const float* cw  = (const float*)d_in[2];
    const float* cbi = (const float*)d_in[3];
    float* ws = (float*)d_ws;
    size_t o = 0;
    float* xt   = ws + o; o += (size_t)B_ * N_ * C_;
    unsigned short* xt16 = (unsigned short*)(ws + o); o += (size_t)B_ * N_ * C_ / 2;
    unsigned short* xt16l = (unsigned short*)(ws + o); o += (size_t)B_ * N_ * C_ / 2;
    unsigned short* Wg16 = (unsigned short*)(ws + o); o += (size_t)OC_ * KC_ / 2;
    float* cent = ws + o; o += (size_t)B_ * M_ * C_;
    unsigned short* cent16 = (unsigned short*)(ws + o); o += (size_t)B_ * M_ * C_ / 2;
    unsigned short* centh = (unsigned short*)(ws + o); o += (size_t)B_ * 64 * C_ / 2;
    unsigned short* centl = (unsigned short*)(ws + o); o += (size_t)B_ * 64 * C_ / 2;
    float* c2   = ws + o; o += (size_t)B_ * M_;
    unsigned short* part = (unsigned short*)(ws + o); o += (size_t)B_ * CH_ * M_ * C_ / 2;
    float* wsp  = ws + o; o += (size_t)B_ * CH_ * M_;
    int* nn = (int*)(ws + o); o += (size_t)B_ * N_ * TK_;
    unsigned short* xjt16  = (unsigned short*)(ws + o); o += (size_t)B_ * N_ * C_ / 2;
    unsigned short* xjct16 = (unsigned short*)(ws + o); o += (size_t)B_ * N_ * C_ / 2;
    float* outp = (float*)d_out;

    k_transpose<<<dim3(218, C_ / 32, B_), dim3(32, 8), 0, stream>>>(x, xt, xt16, xt16l, cw, Wg16);
    k_init_cent<<<dim3(64, B_), dim3(192), 0, stream>>>(xt, cent, c2, centh, centl);
    for (int it = 0; it < 3; it++) {
        k_logits_upd<<<dim3(CH_, B_), dim3(256), 0, stream>>>(xt, xt16, xt16l, cent,
            centh, centl, c2, part, wsp, nn, (it == 2) ? 1 : 0, (it < 2) ? 1 : 0);
        k_upd_reduce<<<dim3(M_, B_), dim3(384), 0, stream>>>(part, wsp, cent, c2,
            cent16, centh, centl, (it == 2) ? 1 : 0);
    }
    k_gather<<<dim3(N_ / GPB, B_), dim3(192), 0, stream>>>(xt16, cent16, edge, nn, xjt16, xjct16);
    k_gemm<<<dim3(N_ / 64, B_), dim3(256), 0, stream>>>(Wg16, xt16, xjt16, xjct16, cbi, outp);
}

// Round 2
// 245.851 us; speedup vs baseline: 1.1794x; 1.0098x over previous
//
#include <hip/hip_runtime.h>
#include <hip/hip_bf16.h>
#include <math.h>

#define B_   4
#define C_   192
#define N_   6400
#define K_   9
#define M_   50
#define TK_  12
#define OC_  192
#define KC_  576     // 3*C
#define CH_  100     // 64-point chunks per batch
#define LSTR 53      // padded lg row stride (fp32; odd -> conflict-free)
#define TSTR 72      // lgT row stride (bf16)
#define XSTR 40      // xT row stride (bf16), 80 B, 16B-aligned
#define GSTR 40      // k_gemm bf16 LDS row stride
#define GPB  8       // points per k_gather block

typedef __bf16 b16x8 __attribute__((ext_vector_type(8)));
typedef float f32x4 __attribute__((ext_vector_type(4)));

__device__ inline unsigned short f2b(float f) {
    union { __hip_bfloat16 h; unsigned short u; } v;
    v.h = __float2bfloat16(f);
    return v.u;
}
__device__ inline float b2f(unsigned short u) {
    union { float f; unsigned int i; } v;
    v.i = ((unsigned int)u) << 16;
    return v.f;
}
__device__ inline void up8(uint4 v, float* f) {
    unsigned int w[4] = {v.x, v.y, v.z, v.w};
#pragma unroll
    for (int i = 0; i < 4; i++) {
        f[2 * i]     = b2f((unsigned short)(w[i] & 0xffffu));
        f[2 * i + 1] = b2f((unsigned short)(w[i] >> 16));
    }
}
__device__ inline uint4 pack8(const float* f) {
    unsigned int w[4];
#pragma unroll
    for (int i = 0; i < 4; i++)
        w[i] = (unsigned int)f2b(f[2 * i]) | ((unsigned int)f2b(f[2 * i + 1]) << 16);
    uint4 v; v.x = w[0]; v.y = w[1]; v.z = w[2]; v.w = w[3];
    return v;
}

// -------- transpose x (b,c,n) -> xt fp32 + xt16/xt16l (bf16 hi/lo)
//          + merged W re-permute (blocks with blockIdx.x >= 200) -------------
__global__ void k_transpose(const float* __restrict__ x, float* __restrict__ xt,
                            unsigned short* __restrict__ xt16,
                            unsigned short* __restrict__ xt16l,
                            const float* __restrict__ cw,
                            unsigned short* __restrict__ Wg16) {
    int tid = threadIdx.y * 32 + threadIdx.x;
    if (blockIdx.x >= 200) {
        // Wg16[o][t*192+ch] = conv_w[o][ch*3+t];  432 blocks x 256 = 110592
        int g = ((blockIdx.x - 200) * 24 + blockIdx.z * 6 + blockIdx.y) * 256 + tid;
        if (g < OC_ * KC_) {
            int r = g % KC_;
            Wg16[g] = f2b(cw[(g / KC_) * KC_ + (r % C_) * 3 + (r / C_)]);
        }
        return;
    }
    __shared__ float tile[32][33];
    int b = blockIdx.z;
    int p0 = blockIdx.x * 32, c0 = blockIdx.y * 32;
    int tx = threadIdx.x, ty = threadIdx.y;
    const float* xb = x + (size_t)b * C_ * N_;
    float* xtb = xt + (size_t)b * N_ * C_;
    unsigned short* xt16b = xt16 + (size_t)b * N_ * C_;
    unsigned short* xt16lb = xt16l + (size_t)b * N_ * C_;
#pragma unroll
    for (int i = 0; i < 4; i++) {
        int cc = ty + 8 * i;
        tile[cc][tx] = xb[(size_t)(c0 + cc) * N_ + p0 + tx];
    }
    __syncthreads();
#pragma unroll
    for (int i = 0; i < 4; i++) {
        int pp = ty + 8 * i;
        float v = tile[tx][pp];
        size_t o = (size_t)(p0 + pp) * C_ + c0 + tx;
        xtb[o] = v;
        unsigned short hi = f2b(v);
        xt16b[o] = hi;
        xt16lb[o] = f2b(v - b2f(hi));
    }
}

// -- initial centroids: 5x10 pool (+ |c|^2, + hi/lo split, zero pad rows) -----
__global__ __launch_bounds__(192) void k_init_cent(const float* __restrict__ xt,
        float* __restrict__ cent, float* __restrict__ c2,
        unsigned short* __restrict__ centh, unsigned short* __restrict__ centl) {
    int m = blockIdx.x, b = blockIdx.y, c = threadIdx.x;
    if (m >= M_) {   // zero-pad rows 50..63 of the split arrays
        size_t o = ((size_t)b * 64 + m) * C_ + c;
        centh[o] = 0; centl[o] = 0;
        return;
    }
    int gy = m / 10, gx = m % 10;
    const float* xtb = xt + (size_t)b * N_ * C_;
    float s = 0.f;
    for (int yy = 0; yy < 16; yy++)
        for (int xx = 0; xx < 8; xx++) {
            int p = (gy * 16 + yy) * 80 + gx * 8 + xx;
            s += xtb[(size_t)p * C_ + c];
        }
    float v = s * (1.f / 128.f);
    cent[((size_t)b * M_ + m) * C_ + c] = v;
    size_t oh = ((size_t)b * 64 + m) * C_ + c;
    unsigned short hi = f2b(v);
    centh[oh] = hi;
    centl[oh] = f2b(v - b2f(hi));
    float q = v * v;
    __shared__ float red[3];
#pragma unroll
    for (int off = 32; off > 0; off >>= 1) q += __shfl_down(q, off, 64);
    if ((c & 63) == 0) red[c >> 6] = q;
    __syncthreads();
    if (c == 0) c2[(size_t)b * M_ + m] = red[0] + red[1] + red[2];
}

// ==== fused: logits (direct-global MFMA fast path / fp32 exact path) +
//      softmax + bf16-split MFMA partials (+ topk on last iter) ==============
// 512 threads (8 waves): phase1 splits m-tiles across wave pairs, phase2
// splits c-tiles across wave pairs -> 2x resident waves vs 256-thr version.
__global__ __launch_bounds__(512) void k_logits_upd(const float* __restrict__ xt,
        const unsigned short* __restrict__ xt16, const unsigned short* __restrict__ xt16l,
        const float* __restrict__ cent,
        const unsigned short* __restrict__ centh, const unsigned short* __restrict__ centl,
        const float* __restrict__ c2g,
        unsigned short* __restrict__ part, float* __restrict__ wsp,
        int* __restrict__ nn, int do_topk, int fast) {
    __shared__ alignas(16) char smem[51712];
    __shared__ float sred[512];
    float* Ac = (float*)smem;                             // fp32 path staging
    float* Bp = (float*)(smem + 4352);
    float* lg = (float*)(smem + 20480);
    unsigned short* lgTh = (unsigned short*)smem;
    unsigned short* lgTl = (unsigned short*)(smem + 9216);
    unsigned short* xTh = (unsigned short*)(smem + 18432);
    unsigned short* xTl = (unsigned short*)(smem + 35072);
    int b = blockIdx.y;
    int blk = blockIdx.x;
    int p0 = blk * 64;
    int tid = threadIdx.x;
    int tx = tid & 15, ty = (tid >> 4) & 15;
    int lr = (tid >> 2) & 63, lq = tid & 3;
    int wave = tid >> 6, lane = tid & 63;
    int m16 = lane & 15, q = lane >> 4;
    const float* xb = xt + ((size_t)b * N_ + p0) * C_;
    const unsigned short* x16b = xt16 + ((size_t)b * N_ + p0) * C_;
    const unsigned short* x16lb = xt16l + ((size_t)b * N_ + p0) * C_;
    if (fast) {
        // ---- phase 1 fast: split-bf16 MFMA logits, fragments direct from
        //      global; wave = (mh, pg): pg = p-col group, mh = m-tile half ----
        const unsigned short* chg = centh + (size_t)b * 64 * C_;
        const unsigned short* clg = centl + (size_t)b * 64 * C_;
        int pg = wave & 3, mh = wave >> 2;
        f32x4 acc1[2];
#pragma unroll
        for (int i = 0; i < 2; i++) acc1[i] = (f32x4){0.f, 0.f, 0.f, 0.f};
#pragma unroll
        for (int kt = 0; kt < 6; kt++) {
            int kg = kt * 32;
            size_t xo = (size_t)(pg * 16 + m16) * C_ + kg + q * 8;
            b16x8 bh = *(const b16x8*)&x16b[xo];
            b16x8 bl = *(const b16x8*)&x16lb[xo];
#pragma unroll
            for (int t = 0; t < 2; t++) {
                int mt = mh * 2 + t;
                size_t co = (size_t)(mt * 16 + m16) * C_ + kg + q * 8;
                b16x8 ah = *(const b16x8*)&chg[co];
                b16x8 al = *(const b16x8*)&clg[co];
                acc1[t] = __builtin_amdgcn_mfma_f32_16x16x32_bf16(ah, bh, acc1[t], 0, 0, 0);
                acc1[t] = __builtin_amdgcn_mfma_f32_16x16x32_bf16(ah, bl, acc1[t], 0, 0, 0);
                acc1[t] = __builtin_amdgcn_mfma_f32_16x16x32_bf16(al, bh, acc1[t], 0, 0, 0);
            }
        }
        // D row m = (mh*2+t)*16+q*4+r, col p = pg*16+m16
#pragma unroll
        for (int t = 0; t < 2; t++) {
#pragma unroll
            for (int r = 0; r < 4; r++) {
                int m = (mh * 2 + t) * 16 + q * 4 + r;
                if (m < M_) {
                    float c2v = c2g[(size_t)b * M_ + m];
                    lg[(pg * 16 + m16) * LSTR + m] = 2.f * acc1[t][r] - c2v;
                }
            }
        }
    } else {
        // ---- phase 1 exact: fp32 VALU logits (iter 2 -> topk); 256 working
        //      threads, upper waves idle through hoisted barriers ----
        const float* cb = cent + (size_t)b * M_ * C_;
        float acc[4][4];
#pragma unroll
        for (int i = 0; i < 4; i++)
#pragma unroll
            for (int j = 0; j < 4; j++) acc[i][j] = 0.f;
        for (int kt = 0; kt < 12; kt++) {
            int kg = kt * 16;
            float4 cv = make_float4(0.f, 0.f, 0.f, 0.f);
            float4 pv = make_float4(0.f, 0.f, 0.f, 0.f);
            if (tid < 256) {
                if (lr < M_) cv = *(const float4*)&cb[(size_t)lr * C_ + kg + 4 * lq];
                pv = *(const float4*)&xb[(size_t)lr * C_ + kg + 4 * lq];
            }
            __syncthreads();
            if (tid < 256) {
                Ac[(4 * lq + 0) * 68 + lr] = cv.x; Ac[(4 * lq + 1) * 68 + lr] = cv.y;
                Ac[(4 * lq + 2) * 68 + lr] = cv.z; Ac[(4 * lq + 3) * 68 + lr] = cv.w;
                Bp[(4 * lq + 0) * 68 + lr] = pv.x; Bp[(4 * lq + 1) * 68 + lr] = pv.y;
                Bp[(4 * lq + 2) * 68 + lr] = pv.z; Bp[(4 * lq + 3) * 68 + lr] = pv.w;
            }
            __syncthreads();
            if (tid < 256) {
#pragma unroll
                for (int kk = 0; kk < 16; kk++) {
                    float4 a = *(const float4*)&Ac[kk * 68 + 4 * ty];
                    float4 bb = *(const float4*)&Bp[kk * 68 + 4 * tx];
                    acc[0][0] += a.x * bb.x; acc[0][1] += a.x * bb.y; acc[0][2] += a.x * bb.z; acc[0][3] += a.x * bb.w;
                    acc[1][0] += a.y * bb.x; acc[1][1] += a.y * bb.y; acc[1][2] += a.y * bb.z; acc[1][3] += a.y * bb.w;
                    acc[2][0] += a.z * bb.x; acc[2][1] += a.z * bb.y; acc[2][2] += a.z * bb.z; acc[2][3] += a.z * bb.w;
                    acc[3][0] += a.w * bb.x; acc[3][1] += a.w * bb.y; acc[3][2] += a.w * bb.z; acc[3][3] += a.w * bb.w;
                }
            }
        }
        __syncthreads();
        if (tid < 256) {
#pragma unroll
            for (int i = 0; i < 4; i++) {
                int m = 4 * ty + i;
                if (m < M_) {
                    float c2v = c2g[(size_t)b * M_ + m];
#pragma unroll
                    for (int j = 0; j < 4; j++)
                        lg[(4 * tx + j) * LSTR + m] = 2.f * acc[i][j] - c2v;
                }
            }
        }
    }
    __syncthreads();
    // ---- softmax (8-way parallel per row) ----
    {
        int p = tid & 63, prt = tid >> 6;
        int m0 = prt * 7;
        int m1 = (m0 + 7 > M_) ? M_ : m0 + 7;
        float* row = &lg[p * LSTR];
        float mx = -1e30f;
        for (int m = m0; m < m1; m++) mx = fmaxf(mx, row[m]);
        sred[prt * 64 + p] = mx;
        __syncthreads();
        mx = -1e30f;
#pragma unroll
        for (int k = 0; k < 8; k++) mx = fmaxf(mx, sred[k * 64 + p]);
        float s = 0.f;
        for (int m = m0; m < m1; m++) {
            float e = expf(row[m] - mx);
            row[m] = e;
            s += e;
        }
        __syncthreads();
        sred[prt * 64 + p] = s;
        __syncthreads();
        s = 0.f;
#pragma unroll
        for (int k = 0; k < 8; k++) s += sred[k * 64 + p];
        float inv = 1.f / s;
        for (int m = m0; m < m1; m++) row[m] *= inv;
    }
    __syncthreads();
    // ---- build lgT[m][p] hi/lo bf16 (lane-consecutive p: conflict-free) ----
    for (int j = tid; j < 64 * 64; j += 512) {
        int m = j >> 6, p = j & 63;
        float w = (m < M_) ? lg[p * LSTR + m] : 0.f;
        unsigned short hi = f2b(w);
        lgTh[m * TSTR + p] = hi;
        lgTl[m * TSTR + p] = f2b(w - b2f(hi));
    }
    __syncthreads();
    // ---- topk on last iteration (reads+destroys lg; before xT overwrites) ---
    if (do_topk && tid < 64) {
        float* row = &lg[tid * LSTR];
        int* nb = nn + ((size_t)b * N_ + p0 + tid) * TK_;
        for (int r = 0; r < TK_; r++) {
            float bv = -1.f;
            int bi = 0;
            for (int m = 0; m < M_; m++) {
                float v = row[m];
                if (v > bv) { bv = v; bi = m; }   // strict > : lowest index wins ties
            }
            nb[r] = bi;
            row[bi] = -1.f;
        }
    }
    // ---- phase 2: part[m][c] = sum_p w*x via 3-term bf16-split MFMA ----
    //      wave = (m-tile, c-half): mt2 = wave>>1, c-tiles cbase..cbase+6
    int mt2 = wave >> 1, cbase = (wave & 1) * 7;
    f32x4 acc2[7];
#pragma unroll
    for (int i = 0; i < 7; i++) acc2[i] = (f32x4){0.f, 0.f, 0.f, 0.f};
    for (int h = 0; h < 2; h++) {
        __syncthreads();   // lg/topk done (h=0); prev MFMA reads done (h=1)
        // xT build: lanes consecutive pl -> contiguous b16 writes (no conflict)
        for (int j = tid; j < 32 * 24; j += 512) {
            int pl = j & 31, ko = (j >> 5) * 8;
            int4 vh = *(const int4*)&x16b[(size_t)(h * 32 + pl) * C_ + ko];
            int4 vl = *(const int4*)&x16lb[(size_t)(h * 32 + pl) * C_ + ko];
            const unsigned short* ph = (const unsigned short*)&vh;
            const unsigned short* pv = (const unsigned short*)&vl;
#pragma unroll
            for (int i = 0; i < 8; i++) {
                xTh[(ko + i) * XSTR + pl] = ph[i];
                xTl[(ko + i) * XSTR + pl] = pv[i];
            }
        }
        for (int j = tid; j < 32 * 16; j += 512) {
            int pl = j & 31, c = C_ + (j >> 5);
            xTh[c * XSTR + pl] = (c == C_) ? f2b(1.f) : 0;
            xTl[c * XSTR + pl] = 0;
        }
        __syncthreads();
        b16x8 ah = *(const b16x8*)&lgTh[(mt2 * 16 + m16) * TSTR + h * 32 + q * 8];
        b16x8 al = *(const b16x8*)&lgTl[(mt2 * 16 + m16) * TSTR + h * 32 + q * 8];
#pragma unroll
        for (int ci = 0; ci < 7; ci++) {
            int ct = cbase + ci;
            if (ct >= 13) continue;
            b16x8 bh = *(const b16x8*)&xTh[(ct * 16 + m16) * XSTR + q * 8];
            b16x8 bl = *(const b16x8*)&xTl[(ct * 16 + m16) * XSTR + q * 8];
            acc2[ci] = __builtin_amdgcn_mfma_f32_16x16x32_bf16(ah, bh, acc2[ci], 0, 0, 0);
            acc2[ci] = __builtin_amdgcn_mfma_f32_16x16x32_bf16(ah, bl, acc2[ci], 0, 0, 0);
            acc2[ci] = __builtin_amdgcn_mfma_f32_16x16x32_bf16(al, bh, acc2[ci], 0, 0, 0);
        }
    }
    // ---- epilogue: D row m = mt2*16 + q*4 + r, col c = ct*16 + m16 ----
    unsigned short* pb = part + ((size_t)b * CH_ + blk) * (size_t)(M_ * C_);
    int mbase = mt2 * 16 + q * 4;
#pragma unroll
    for (int ci = 0; ci < 7; ci++) {
        int ct = cbase + ci;
        if (ct >= 13) continue;
        int c = ct * 16 + m16;
#pragma unroll
        for (int r = 0; r < 4; r++) {
            int mm = mbase + r;
            if (mm >= M_) continue;
            float v = acc2[ci][r];
            if (c < C_) pb[(size_t)mm * C_ + c] = f2b(v);
            else if (c == C_) wsp[((size_t)b * CH_ + blk) * M_ + mm] = v;
        }
    }
}

// ---- chunk reduction: 4-way chunk split (768 thr) + wave-parallel wsp sum ---
__global__ __launch_bounds__(768) void k_upd_reduce(const unsigned short* __restrict__ part,
        const float* __restrict__ wsp, float* __restrict__ cent, float* __restrict__ c2,
        unsigned short* __restrict__ cent16,
        unsigned short* __restrict__ centh, unsigned short* __restrict__ centl, int last) {
    int m = blockIdx.x, b = blockIdx.y;
    int tid = threadIdx.x;
    int c = tid % 192, g = tid / 192;   // g = 0..3
    __shared__ float pred[3][192];
    __shared__ float sws;
    __shared__ float red[3];
    // each quarter sums 25 of the 100 chunks
    const unsigned short* pp = part + (((size_t)b * CH_ + (size_t)g * 25) * M_ + m) * (size_t)C_ + c;
    float s = 0.f;
    for (int ch = 0; ch < 25; ch++)
        s += b2f(pp[(size_t)ch * M_ * C_]);
    if (g) pred[g - 1][c] = s;
    // wave-parallel wsp reduction (lanes 0..63 cover 100 chunks in <=2 loads)
    if (tid < 64) {
        float w = wsp[((size_t)b * CH_ + tid) * M_ + m];
        if (tid + 64 < CH_) w += wsp[((size_t)b * CH_ + tid + 64) * M_ + m];
#pragma unroll
        for (int off = 32; off > 0; off >>= 1) w += __shfl_down(w, off, 64);
        if (tid == 0) sws = w + 1e-8f;
    }
    __syncthreads();
    if (g == 0) {
        float v = (s + pred[0][c] + pred[1][c] + pred[2][c]) / sws;
        size_t o = ((size_t)b * M_ + m) * C_ + c;
        cent[o] = v;
        if (last) cent16[o] = f2b(v);
        size_t oh = ((size_t)b * 64 + m) * C_ + c;
        unsigned short hi = f2b(v);
        centh[oh] = hi;
        centl[oh] = f2b(v - b2f(hi));
        float q = v * v;
#pragma unroll
        for (int off = 32; off > 0; off >>= 1) q += __shfl_down(q, off, 64);
        if ((c & 63) == 0) red[c >> 6] = q;
    }
    __syncthreads();
    if (tid == 0) c2[(size_t)b * M_ + m] = red[0] + red[1] + red[2];
}

// ---------------- gathers (bf16 sources): edge max-rel + topk-centroid max ---
// vectorized: uint4 = 8 channels/lane, 24 lanes/point, 8 points/block
__global__ __launch_bounds__(192) void k_gather(const unsigned short* __restrict__ xt16,
        const unsigned short* __restrict__ cent16, const int* __restrict__ edge,
        const int* __restrict__ nn, unsigned short* __restrict__ xjt16,
        unsigned short* __restrict__ xjct16) {
    __shared__ int sidx[GPB * (2 * K_ + TK_)];
    int b = blockIdx.y;
    int p0 = blockIdx.x * GPB;
    int tid = threadIdx.x;
    for (int j = tid; j < GPB * (2 * K_ + TK_); j += 192) {
        int g = j / (2 * K_ + TK_), r = j % (2 * K_ + TK_);
        size_t base = (size_t)b * N_ + p0 + g;
        int v;
        if (r < K_) v = edge[base * K_ + r];
        else if (r < 2 * K_) v = edge[(size_t)B_ * N_ * K_ + base * K_ + (r - K_)];
        else v = nn[base * TK_ + (r - 2 * K_)];
        sidx[j] = v;
    }
    __syncthreads();
    int g = tid / 24, t = tid % 24;
    int ch0 = t * 8;
    int p = p0 + g;
    const unsigned short* xb = xt16 + (size_t)b * N_ * C_;
    const unsigned short* cb = cent16 + (size_t)b * M_ * C_;
    const int* si = &sidx[g * (2 * K_ + TK_)];
    float xv[8], ta[8], tb[8], mj[8], mc[8];
    up8(*(const uint4*)&xb[(size_t)p * C_ + ch0], xv);
#pragma unroll
    for (int e = 0; e < 8; e++) { mj[e] = -1e30f; mc[e] = -1e30f; }
#pragma unroll
    for (int kk = 0; kk < K_; kk++) {
        up8(*(const uint4*)&xb[(size_t)si[kk] * C_ + ch0], ta);
        up8(*(const uint4*)&xb[(size_t)si[K_ + kk] * C_ + ch0], tb);
#pragma unroll
        for (int e = 0; e < 8; e++) mj[e] = fmaxf(mj[e], ta[e] - tb[e]);
    }
#pragma unroll
    for (int kk = 0; kk < TK_; kk++) {
        up8(*(const uint4*)&cb[(size_t)si[2 * K_ + kk] * C_ + ch0], ta);
#pragma unroll
        for (int e = 0; e < 8; e++) mc[e] = fmaxf(mc[e], ta[e]);
    }
#pragma unroll
    for (int e = 0; e < 8; e++) mc[e] -= xv[e];
    size_t o = ((size_t)b * N_ + p) * C_ + ch0;
    *(uint4*)&xjt16[o] = pack8(mj);
    *(uint4*)&xjct16[o] = pack8(mc);
}

// ------- final conv via bf16 MFMA: full-OC 192(o) x 64(p) tile, feat read once
__global__ __launch_bounds__(256) void k_gemm(const unsigned short* __restrict__ Wg16,
        const unsigned short* __restrict__ xt16, const unsigned short* __restrict__ xjt16,
        const unsigned short* __restrict__ xjct16, const float* __restrict__ bias,
        float* __restrict__ out) {
    __shared__ short As[192 * GSTR];   // Wg k-chunk [o][32k]
    __shared__ short Bs[64 * GSTR];    // feat k-chunk [p][32k]
    int b = blockIdx.y;
    int po = blockIdx.x * 64;
    int tid = threadIdx.x;
    int wave = tid >> 6, lane = tid & 63;
    int m16 = lane & 15, q = lane >> 4;
    const unsigned short* s0 = xt16 + (size_t)b * N_ * C_;
    const unsigned short* s1 = xjt16 + (size_t)b * N_ * C_;
    const unsigned short* s2 = xjct16 + (size_t)b * N_ * C_;
    f32x4 acc[12];
#pragma unroll
    for (int i = 0; i < 12; i++) acc[i] = (f32x4){0.f, 0.f, 0.f, 0.f};
    int brow = tid >> 2, bch = tid & 3;
    for (int kt = 0; kt < 18; kt++) {
        int kg = kt * 32;
        int prt = kg / C_, koff = kg - prt * C_;
        const unsigned short* src = (prt == 0) ? s0 : ((prt == 1) ? s1 : s2);
        int4 av[3];
#pragma unroll
        for (int t = 0; t < 3; t++) {
            int idx = t * 256 + tid;
            av[t] = *(const int4*)&Wg16[(size_t)(idx >> 2) * KC_ + kg + (idx & 3) * 8];
        }
        int4 bv = *(const int4*)&src[(size_t)(po + brow) * C_ + koff + bch * 8];
        __syncthreads();
#pragma unroll
        for (int t = 0; t < 3; t++) {
            int idx = t * 256 + tid;
            *(int4*)&As[(idx >> 2) * GSTR + (idx & 3) * 8] = av[t];
        }
        *(int4*)&Bs[brow * GSTR + bch * 8] = bv;
        __syncthreads();
        b16x8 bf = *(const b16x8*)&Bs[(wave * 16 + m16) * GSTR + q * 8];
#pragma unroll
        for (int of = 0; of < 12; of++) {
            b16x8 af = *(const b16x8*)&As[(of * 16 + m16) * GSTR + q * 8];
            acc[of] = __builtin_amdgcn_mfma_f32_16x16x32_bf16(af, bf, acc[of], 0, 0, 0);
        }
    }
    int p = po + wave * 16 + m16;
#pragma unroll
    for (int of = 0; of < 12; of++) {
        int o = of * 16 + q * 4;
        float4 bv = *(const float4*)&bias[o];
        float bia[4] = {bv.x, bv.y, bv.z, bv.w};
#pragma unroll
        for (int r = 0; r < 4; r++)
            out[((size_t)b * OC_ + o + r) * N_ + p] = fmaxf(acc[of][r] + bia[r], 0.f);
    }
}

extern "C" void kernel_launch(void* const* d_in, const int* in_sizes, int n_in,
                              void* d_out, int out_size, void* d_ws, size_t ws_size,
                              hipStream_t stream) {
    (void)in_sizes; (void)n_in; (void)out_size; (void)ws_size;
    const float* x   = (const float*)d_in[0];
    const int* edge  = (const int*)d_in[1];
    const float* cw  = (const float*)d_in[2];
    const float* cbi = (const float*)d_in[3];
    float* ws = (float*)d_ws;
    size_t o = 0;
    float* xt   = ws + o; o += (size_t)B_ * N_ * C_;
    unsigned short* xt16 = (unsigned short*)(ws + o); o += (size_t)B_ * N_ * C_ / 2;
    unsigned short* xt16l = (unsigned short*)(ws + o); o += (size_t)B_ * N_ * C_ / 2;
    unsigned short* Wg16 = (unsigned short*)(ws + o); o += (size_t)OC_ * KC_ / 2;
    float* cent = ws + o; o += (size_t)B_ * M_ * C_;
    unsigned short* cent16 = (unsigned short*)(ws + o); o += (size_t)B_ * M_ * C_ / 2;
    unsigned short* centh = (unsigned short*)(ws + o); o += (size_t)B_ * 64 * C_ / 2;
    unsigned short* centl = (unsigned short*)(ws + o); o += (size_t)B_ * 64 * C_ / 2;
    float* c2   = ws + o; o += (size_t)B_ * M_;
    unsigned short* part = (unsigned short*)(ws + o); o += (size_t)B_ * CH_ * M_ * C_ / 2;
    float* wsp  = ws + o; o += (size_t)B_ * CH_ * M_;
    int* nn = (int*)(ws + o); o += (size_t)B_ * N_ * TK_;
    unsigned short* xjt16  = (unsigned short*)(ws + o); o += (size_t)B_ * N_ * C_ / 2;
    unsigned short* xjct16 = (unsigned short*)(ws + o); o += (size_t)B_ * N_ * C_ / 2;
    float* outp = (float*)d_out;

    k_transpose<<<dim3(218, C_ / 32, B_), dim3(32, 8), 0, stream>>>(x, xt, xt16, xt16l, cw, Wg16);
    k_init_cent<<<dim3(64, B_), dim3(192), 0, stream>>>(xt, cent, c2, centh, centl);
    for (int it = 0; it < 3; it++) {
        k_logits_upd<<<dim3(CH_, B_), dim3(512), 0, stream>>>(xt, xt16, xt16l, cent,
            centh, centl, c2, part, wsp, nn, (it == 2) ? 1 : 0, (it < 2) ? 1 : 0);
        k_upd_reduce<<<dim3(M_, B_), dim3(768), 0, stream>>>(part, wsp, cent, c2,
            cent16, centh, centl, (it == 2) ? 1 : 0);
    }
    k_gather<<<dim3(N_ / GPB, B_), dim3(192), 0, stream>>>(xt16, cent16, edge, nn, xjt16, xjct16);
    k_gemm<<<dim3(N_ / 64, B_), dim3(256), 0, stream>>>(Wg16, xt16, xjt16, xjct16, cbi, outp);
}